// Round 8
// baseline (970.543 us; speedup 1.0000x reference)
//
#include <hip/hip_runtime.h>

#define BB 512
#define TT 200
#define VV 2048
#define EE 20
#define HH 100
#define G4 400   // 4*H
#define II 64
#define AA 32

typedef _Float16 half8 __attribute__((ext_vector_type(8)));
typedef float    f32x4 __attribute__((ext_vector_type(4)));
typedef float    vf2   __attribute__((ext_vector_type(2)));

#define NCHUNK 64          // K chunks of 32
// ---------------- workspace layout (4B units) ----------------
// [0..1023]            off[513] + pad
// [1024..1024+32767]   Bfrag: 65536 fp16 (64 chunks x 2 etiles x 64 lanes x 8)
// [33792.. ]           emb[512][200][20] fp32
#define WS_BF_OFF  1024
#define WS_EMB_OFF (1024 + 32768)

// ---------------- Kernel 0: prefix-sum of lengths + B-fragment pack (FROZEN) ----------------
__global__ __launch_bounds__(512) void k0_prep(
    const int* __restrict__ lengths, const float* __restrict__ W_emb,
    int* __restrict__ off, _Float16* __restrict__ Bfrag)
{
    if (blockIdx.x == 0) {
        __shared__ int s[BB];
        int tid = threadIdx.x;
        s[tid] = lengths[tid];
        __syncthreads();
        for (int d = 1; d < BB; d <<= 1) {
            int v = (tid >= d) ? s[tid - d] : 0;
            __syncthreads();
            if (tid >= d) s[tid] += v;
            __syncthreads();
        }
        off[tid + 1] = s[tid];
        if (tid == 0) off[0] = 0;
    } else {
        int F = (blockIdx.x - 1) * 512 + threadIdx.x;   // < 65536
        if (F < NCHUNK * 2 * 64 * 8) {
            int e = F & 7, l = (F >> 3) & 63, n = (F >> 9) & 1, c = F >> 10;
            int k = c * 32 + (l >> 4) * 8 + e;
            int col = n * 16 + (l & 15);
            float v = (col < EE) ? W_emb[(size_t)col * VV + k] : 0.f;
            Bfrag[F] = (_Float16)v;
        }
    }
}

// ---------------- Kernel 1: embedding GEMM via MFMA fp16, zero LDS (FROZEN) ----------------
__global__ __launch_bounds__(256) void k1_embed(
    const float* __restrict__ batch, const int* __restrict__ off,
    const _Float16* __restrict__ Bfrag, const float* __restrict__ b_emb,
    float* __restrict__ emb)
{
    const int Nv = off[BB];
    if (blockIdx.x * 64 >= Nv) return;

    const int lane  = threadIdx.x & 63;
    const int wid   = threadIdx.x >> 6;
    const int rbase = blockIdx.x * 64 + wid * 16;

    int lrow = rbase + (lane & 15);
    int lr = (lrow < Nv) ? lrow : (Nv - 1);
    int lo = 0, hi = BB;
    while (lo + 1 < hi) {
        int mid = (lo + hi) >> 1;
        if (off[mid] <= lr) lo = mid; else hi = mid;
    }
    const int lroff = lo * TT + (lr - off[lo]);   // (b*TT + t) for this row

    const float* __restrict__ aptr = batch + (size_t)lroff * VV + ((lane >> 4) * 8);
    const half8* __restrict__ bptr = reinterpret_cast<const half8*>(Bfrag) + lane;

    f32x4 acc0 = {0.f, 0.f, 0.f, 0.f};
    f32x4 acc1 = {0.f, 0.f, 0.f, 0.f};

#pragma unroll 4
    for (int c = 0; c < NCHUNK; ++c) {
        float4 a0 = *reinterpret_cast<const float4*>(aptr + c * 32);
        float4 a1 = *reinterpret_cast<const float4*>(aptr + c * 32 + 4);
        half8 b0 = bptr[(c * 2 + 0) * 64];
        half8 b1 = bptr[(c * 2 + 1) * 64];
        half8 av;
        av[0] = (_Float16)a0.x; av[1] = (_Float16)a0.y;
        av[2] = (_Float16)a0.z; av[3] = (_Float16)a0.w;
        av[4] = (_Float16)a1.x; av[5] = (_Float16)a1.y;
        av[6] = (_Float16)a1.z; av[7] = (_Float16)a1.w;
        acc0 = __builtin_amdgcn_mfma_f32_16x16x32_f16(av, b0, acc0, 0, 0, 0);
        acc1 = __builtin_amdgcn_mfma_f32_16x16x32_f16(av, b1, acc1, 0, 0, 0);
    }

    const int col0 = lane & 15;
    const float bias0 = b_emb[col0];
    const float bias1 = (col0 < 4) ? b_emb[16 + col0] : 0.f;
#pragma unroll
    for (int r = 0; r < 4; ++r) {
        int s = (lane >> 4) * 4 + r;
        int srow = rbase + s;
        int sroff = __shfl(lroff, s, 64);
        if (srow < Nv) {
            emb[(size_t)sroff * EE + col0] = acc0[r] + bias0;
            if (col0 < 4)
                emb[(size_t)sroff * EE + 16 + col0] = acc1[r] + bias1;
        }
    }
}

// ---------------- Kernel 2: R7 version (FROZEN) — launched 3x to measure ----------------
__device__ __forceinline__ float fast_sig(float x) { return 1.f / (1.f + __expf(-x)); }
__device__ __forceinline__ float fast_tanh(float x) {
    x = fminf(fmaxf(x, -15.f), 15.f);
    float e = __expf(2.f * x);
    return (e - 1.f) / (e + 1.f);
}
__device__ __forceinline__ float dpp_xor1_add(float v) {
    int p = __builtin_amdgcn_update_dpp(0, __builtin_bit_cast(int, v), 0xB1, 0xF, 0xF, true);
    return v + __builtin_bit_cast(float, p);
}
__device__ __forceinline__ float dpp_xor2_add(float v) {
    int p = __builtin_amdgcn_update_dpp(0, __builtin_bit_cast(int, v), 0x4E, 0xF, 0xF, true);
    return v + __builtin_bit_cast(float, p);
}
#define QSTR 36   // quarter stride in xh buffer (floats): conflict-free across q

__global__ __launch_bounds__(448) void k2_lstm(
    const float* __restrict__ emb, const int* __restrict__ lengths,
    const float* __restrict__ W_ih, const float* __restrict__ W_hh,
    const float* __restrict__ b_ih, const float* __restrict__ b_hh,
    const float* __restrict__ W1, const float* __restrict__ b1,
    const float* __restrict__ W2, const float* __restrict__ b2,
    const float* __restrict__ h0, const float* __restrict__ c0,
    float* __restrict__ out)
{
    __shared__ float emb_lds[2][TT][EE];   // 32000 B, staged once
    __shared__ float xhbuf[2][2][160];     // [buf][batch][4 quarters x QSTR]
    __shared__ float hfin[2][HH];
    __shared__ float inter[2][II];

    const int tid = threadIdx.x;
    const int b0  = blockIdx.x * 2;
    const int len0 = lengths[b0];
    const int len1 = lengths[b0 + 1];
    const int tmax = (len0 > len1) ? len0 : len1;

    const int j = tid >> 2, q = tid & 3;

    // stage emb for both batches into LDS (removes all in-loop VMEM)
    {
        const float4* srcp = reinterpret_cast<const float4*>(emb + (size_t)b0 * TT * EE);
        float4* dst = reinterpret_cast<float4*>(&emb_lds[0][0][0]);
        for (int i = tid; i < 2 * TT * EE / 4; i += 448) dst[i] = srcp[i];
    }
    for (int i = tid; i < 2 * 2 * 160; i += 448) (&xhbuf[0][0][0])[i] = 0.f;

    vf2 w2[4][16];
    float biasv[4];
    float c_reg = 0.f;
    int lenq = 0;
    if (tid < G4) {
        const int rr[4] = { j, HH + j, 2 * HH + j, 3 * HH + j };
#pragma unroll
        for (int g = 0; g < 4; ++g) {
            const int r = rr[g];
#pragma unroll
            for (int mp = 0; mp < 16; ++mp) {
                int k = q * 32 + mp * 2;
                float2 v;
                if (k + 1 < EE)           v = *reinterpret_cast<const float2*>(&W_ih[r * EE + k]);
                else if (k + 1 < EE + HH) v = *reinterpret_cast<const float2*>(&W_hh[r * HH + k - EE]);
                else                      v = make_float2(0.f, 0.f);
                w2[g][mp].x = v.x; w2[g][mp].y = v.y;
            }
            biasv[g] = b_ih[r] + b_hh[r];
        }
        if (q < 2) c_reg = c0[(size_t)(b0 + q) * HH + j];
        lenq = (q == 0) ? len0 : len1;
    }
    __syncthreads();   // emb_lds + zeros ready

    if (tid < G4) {
        if (q < 2) {
            int i = EE + j;
            xhbuf[0][q][(i >> 5) * QSTR + (i & 31)] = h0[(size_t)(b0 + q) * HH + j];
        }
    } else if (tid < G4 + 2 * EE) {
        const int wdx = tid - G4, bw = wdx / EE, e = wdx - bw * EE;
        xhbuf[0][bw][e] = emb_lds[bw][0][e];
    }
    __syncthreads();

#pragma unroll 1
    for (int t = 0; t < tmax; ++t) {
        const int cur = t & 1, nxt = cur ^ 1;
        if (tid < G4) {
            vf2 a[4][2];
#pragma unroll
            for (int g = 0; g < 4; ++g) { a[g][0].x=0.f; a[g][0].y=0.f; a[g][1].x=0.f; a[g][1].y=0.f; }
            const float* xc = &xhbuf[cur][0][0];
#pragma unroll
            for (int m8 = 0; m8 < 8; ++m8) {
                float4 x0 = *reinterpret_cast<const float4*>(xc + q * QSTR + m8 * 4);
                float4 x1 = *reinterpret_cast<const float4*>(xc + 160 + q * QSTR + m8 * 4);
                vf2 xl0, xh0, xl1, xh1;
                xl0.x = x0.x; xl0.y = x0.y;  xh0.x = x0.z; xh0.y = x0.w;
                xl1.x = x1.x; xl1.y = x1.y;  xh1.x = x1.z; xh1.y = x1.w;
#pragma unroll
                for (int g = 0; g < 4; ++g) {
                    a[g][0] = __builtin_elementwise_fma(w2[g][2*m8],   xl0, a[g][0]);
                    a[g][0] = __builtin_elementwise_fma(w2[g][2*m8+1], xh0, a[g][0]);
                    a[g][1] = __builtin_elementwise_fma(w2[g][2*m8],   xl1, a[g][1]);
                    a[g][1] = __builtin_elementwise_fma(w2[g][2*m8+1], xh1, a[g][1]);
                }
            }
            float s_[4][2];
#pragma unroll
            for (int g = 0; g < 4; ++g) {
#pragma unroll
                for (int bb = 0; bb < 2; ++bb) {
                    float v = a[g][bb].x + a[g][bb].y;
                    v = dpp_xor1_add(v);
                    v = dpp_xor2_add(v);
                    s_[g][bb] = v;
                }
            }
            if (q < 2) {
                float gi = s_[0][q] + biasv[0];
                float gf = s_[1][q] + biasv[1];
                float gg = s_[2][q] + biasv[2];
                float go = s_[3][q] + biasv[3];
                c_reg = fast_sig(gf) * c_reg + fast_sig(gi) * fast_tanh(gg);
                float hv = fast_sig(go) * fast_tanh(c_reg);
                int ii = EE + j;
                xhbuf[nxt][q][(ii >> 5) * QSTR + (ii & 31)] = hv;
                if (t == lenq - 1) hfin[q][j] = hv;
            }
        } else if (tid < G4 + 2 * EE) {
            const int wdx = tid - G4, bw = wdx / EE, e = wdx - bw * EE;
            if (t + 1 < TT) xhbuf[nxt][bw][e] = emb_lds[bw][t + 1][e];
        }
        __syncthreads();
    }

    if (tid < 2 * II) {
        int bb = tid >> 6, i = tid & 63;
        float a = b1[i];
        const float* w1r = W1 + i * HH;
#pragma unroll
        for (int k = 0; k < HH; k += 4) {
            a += w1r[k] * hfin[bb][k] + w1r[k+1] * hfin[bb][k+1]
               + w1r[k+2] * hfin[bb][k+2] + w1r[k+3] * hfin[bb][k+3];
        }
        inter[bb][i] = fmaxf(a, 0.f);
    }
    __syncthreads();
    if (tid < 2 * AA) {
        int bb = tid >> 5, ai = tid & 31;
        float a = b2[ai];
        const float* w2r = W2 + ai * II;
#pragma unroll
        for (int k = 0; k < II; ++k) a += w2r[k] * inter[bb][k];
        out[(size_t)(b0 + bb) * AA + ai] = a;
    }
}

extern "C" void kernel_launch(void* const* d_in, const int* in_sizes, int n_in,
                              void* d_out, int out_size, void* d_ws, size_t ws_size,
                              hipStream_t stream) {
    const float* batch  = (const float*)d_in[0];
    const int*   lengths= (const int*)  d_in[1];
    const float* W_emb  = (const float*)d_in[2];
    const float* b_emb  = (const float*)d_in[3];
    const float* W_ih   = (const float*)d_in[4];
    const float* W_hh   = (const float*)d_in[5];
    const float* b_ih   = (const float*)d_in[6];
    const float* b_hh   = (const float*)d_in[7];
    const float* W1     = (const float*)d_in[8];
    const float* b1     = (const float*)d_in[9];
    const float* W2     = (const float*)d_in[10];
    const float* b2     = (const float*)d_in[11];
    const float* h0     = (const float*)d_in[12];
    const float* c0     = (const float*)d_in[13];
    float* out = (float*)d_out;

    int*       off   = (int*)d_ws;
    _Float16*  Bfrag = (_Float16*)((float*)d_ws + WS_BF_OFF);
    float*     emb   = (float*)d_ws + WS_EMB_OFF;

    k0_prep<<<1 + (NCHUNK * 2 * 64 * 8 + 511) / 512, 512, 0, stream>>>(lengths, W_emb, off, Bfrag);
    k1_embed<<<(BB * TT + 63) / 64, 256, 0, stream>>>(batch, off, Bfrag, b_emb, emb);
    // MEASUREMENT: k2 is idempotent; launch 3x. k2_dur = (total - 402us) / 2.
    k2_lstm<<<BB / 2, 448, 0, stream>>>(emb, lengths, W_ih, W_hh, b_ih, b_hh,
                                        W1, b1, W2, b2, h0, c0, out);
    k2_lstm<<<BB / 2, 448, 0, stream>>>(emb, lengths, W_ih, W_hh, b_ih, b_hh,
                                        W1, b1, W2, b2, h0, c0, out);
    k2_lstm<<<BB / 2, 448, 0, stream>>>(emb, lengths, W_ih, W_hh, b_ih, b_hh,
                                        W1, b1, W2, b2, h0, c0, out);
}

// Round 9
// 453.787 us; speedup vs baseline: 2.1388x; 2.1388x over previous
//
#include <hip/hip_runtime.h>

#define BB 512
#define TT 200
#define VV 2048
#define EE 20
#define HH 100
#define G4 400   // 4*H
#define II 64
#define AA 32

typedef _Float16 half8 __attribute__((ext_vector_type(8)));
typedef float    f32x4 __attribute__((ext_vector_type(4)));

#define NCHUNK 64          // K chunks of 32
// ---------------- workspace layout (4B units) ----------------
#define WS_BF_OFF  1024
#define WS_EMB_OFF (1024 + 32768)

// ---------------- Kernel 0: prefix-sum of lengths + B-fragment pack (FROZEN) ----------------
__global__ __launch_bounds__(512) void k0_prep(
    const int* __restrict__ lengths, const float* __restrict__ W_emb,
    int* __restrict__ off, _Float16* __restrict__ Bfrag)
{
    if (blockIdx.x == 0) {
        __shared__ int s[BB];
        int tid = threadIdx.x;
        s[tid] = lengths[tid];
        __syncthreads();
        for (int d = 1; d < BB; d <<= 1) {
            int v = (tid >= d) ? s[tid - d] : 0;
            __syncthreads();
            if (tid >= d) s[tid] += v;
            __syncthreads();
        }
        off[tid + 1] = s[tid];
        if (tid == 0) off[0] = 0;
    } else {
        int F = (blockIdx.x - 1) * 512 + threadIdx.x;   // < 65536
        if (F < NCHUNK * 2 * 64 * 8) {
            int e = F & 7, l = (F >> 3) & 63, n = (F >> 9) & 1, c = F >> 10;
            int k = c * 32 + (l >> 4) * 8 + e;
            int col = n * 16 + (l & 15);
            float v = (col < EE) ? W_emb[(size_t)col * VV + k] : 0.f;
            Bfrag[F] = (_Float16)v;
        }
    }
}

// ---------------- Kernel 1: embedding GEMM via MFMA fp16, zero LDS (FROZEN) ----------------
__global__ __launch_bounds__(256) void k1_embed(
    const float* __restrict__ batch, const int* __restrict__ off,
    const _Float16* __restrict__ Bfrag, const float* __restrict__ b_emb,
    float* __restrict__ emb)
{
    const int Nv = off[BB];
    if (blockIdx.x * 64 >= Nv) return;

    const int lane  = threadIdx.x & 63;
    const int wid   = threadIdx.x >> 6;
    const int rbase = blockIdx.x * 64 + wid * 16;

    int lrow = rbase + (lane & 15);
    int lr = (lrow < Nv) ? lrow : (Nv - 1);
    int lo = 0, hi = BB;
    while (lo + 1 < hi) {
        int mid = (lo + hi) >> 1;
        if (off[mid] <= lr) lo = mid; else hi = mid;
    }
    const int lroff = lo * TT + (lr - off[lo]);   // (b*TT + t) for this row

    const float* __restrict__ aptr = batch + (size_t)lroff * VV + ((lane >> 4) * 8);
    const half8* __restrict__ bptr = reinterpret_cast<const half8*>(Bfrag) + lane;

    f32x4 acc0 = {0.f, 0.f, 0.f, 0.f};
    f32x4 acc1 = {0.f, 0.f, 0.f, 0.f};

#pragma unroll 4
    for (int c = 0; c < NCHUNK; ++c) {
        float4 a0 = *reinterpret_cast<const float4*>(aptr + c * 32);
        float4 a1 = *reinterpret_cast<const float4*>(aptr + c * 32 + 4);
        half8 b0 = bptr[(c * 2 + 0) * 64];
        half8 b1 = bptr[(c * 2 + 1) * 64];
        half8 av;
        av[0] = (_Float16)a0.x; av[1] = (_Float16)a0.y;
        av[2] = (_Float16)a0.z; av[3] = (_Float16)a0.w;
        av[4] = (_Float16)a1.x; av[5] = (_Float16)a1.y;
        av[6] = (_Float16)a1.z; av[7] = (_Float16)a1.w;
        acc0 = __builtin_amdgcn_mfma_f32_16x16x32_f16(av, b0, acc0, 0, 0, 0);
        acc1 = __builtin_amdgcn_mfma_f32_16x16x32_f16(av, b1, acc1, 0, 0, 0);
    }

    const int col0 = lane & 15;
    const float bias0 = b_emb[col0];
    const float bias1 = (col0 < 4) ? b_emb[16 + col0] : 0.f;
#pragma unroll
    for (int r = 0; r < 4; ++r) {
        int s = (lane >> 4) * 4 + r;
        int srow = rbase + s;
        int sroff = __shfl(lroff, s, 64);
        if (srow < Nv) {
            emb[(size_t)sroff * EE + col0] = acc0[r] + bias0;
            if (col0 < 4)
                emb[(size_t)sroff * EE + 16 + col0] = acc1[r] + bias1;
        }
    }
}

// ---------------- Kernel 2: 1 batch/block, fp16 weights via v_fma_mix, 2 blocks/CU ----
__device__ __forceinline__ float fast_sig(float x) { return 1.f / (1.f + __expf(-x)); }
__device__ __forceinline__ float dpp_xor1_add(float v) {
    int p = __builtin_amdgcn_update_dpp(0, __builtin_bit_cast(int, v), 0xB1, 0xF, 0xF, true);
    return v + __builtin_bit_cast(float, p);
}
__device__ __forceinline__ float dpp_xor2_add(float v) {
    int p = __builtin_amdgcn_update_dpp(0, __builtin_bit_cast(int, v), 0x4E, 0xF, 0xF, true);
    return v + __builtin_bit_cast(float, p);
}
template<int CTRL>
__device__ __forceinline__ float dpp_mov(float v) {
    int p = __builtin_amdgcn_update_dpp(0, __builtin_bit_cast(int, v), CTRL, 0xF, 0xF, true);
    return __builtin_bit_cast(float, p);
}
// acc += f16(lo/hi of w) * x   (fp32 accumulate, full-rate VALU)
__device__ __forceinline__ void fma_mix_lo(float& acc, unsigned int w, float x) {
    asm("v_fma_mix_f32 %0, %1, %2, %0 op_sel_hi:[1,0,0]"
        : "+v"(acc) : "v"(w), "v"(x));
}
__device__ __forceinline__ void fma_mix_hi(float& acc, unsigned int w, float x) {
    asm("v_fma_mix_f32 %0, %1, %2, %0 op_sel:[1,0,0] op_sel_hi:[1,0,0]"
        : "+v"(acc) : "v"(w), "v"(x));
}
__device__ __forceinline__ unsigned int packw(float f0, float f1) {
    unsigned short u0 = __builtin_bit_cast(unsigned short, (_Float16)f0);
    unsigned short u1 = __builtin_bit_cast(unsigned short, (_Float16)f1);
    return ((unsigned int)u1 << 16) | u0;
}
#define QSTR 36   // quarter stride (floats): 4 quarter bases hit disjoint bank groups

__global__ __launch_bounds__(448, 4) void k2_lstm(
    const float* __restrict__ emb, const int* __restrict__ lengths,
    const float* __restrict__ W_ih, const float* __restrict__ W_hh,
    const float* __restrict__ b_ih, const float* __restrict__ b_hh,
    const float* __restrict__ W1, const float* __restrict__ b1,
    const float* __restrict__ W2, const float* __restrict__ b2,
    const float* __restrict__ h0, const float* __restrict__ c0,
    float* __restrict__ out)
{
    __shared__ float emb_lds[TT][EE];     // 16000 B
    __shared__ float xh[2][160];          // padded concat [x(20);h(100);0] in 4x36 quarters
    __shared__ float hfin[HH];
    __shared__ float inter[II];

    const int tid = threadIdx.x;
    const int b   = blockIdx.x;
    const int len = lengths[b];

    const int j = tid >> 2, q = tid & 3;

    // stage this batch's emb into LDS
    {
        const float4* srcp = reinterpret_cast<const float4*>(emb + (size_t)b * TT * EE);
        float4* dst = reinterpret_cast<float4*>(&emb_lds[0][0]);
        for (int i = tid; i < TT * EE / 4; i += 448) dst[i] = srcp[i];
    }
    for (int i = tid; i < 2 * 160; i += 448) (&xh[0][0])[i] = 0.f;

    // fp16-packed weights: gate g, quarter q, 16 slot-pairs
    unsigned int w[4][16];
    float biasv[4];
    float c_reg = 0.f;
    if (tid < G4) {
#pragma unroll
        for (int g = 0; g < 4; ++g) {
            const int r = g * HH + j;
#pragma unroll
            for (int p = 0; p < 16; ++p) {
                int s0 = q * 32 + 2 * p;
                float f0 = (s0 < EE) ? W_ih[r * EE + s0]
                         : (s0 < EE + HH) ? W_hh[r * HH + s0 - EE] : 0.f;
                int s1 = s0 + 1;
                float f1 = (s1 < EE) ? W_ih[r * EE + s1]
                         : (s1 < EE + HH) ? W_hh[r * HH + s1 - EE] : 0.f;
                w[g][p] = packw(f0, f1);
            }
            biasv[g] = b_ih[r] + b_hh[r];
        }
        if (q == 0) c_reg = c0[(size_t)b * HH + j];
    }
    __syncthreads();   // emb_lds + zeros ready

    if (tid < G4) {
        if (q == 0) {
            int s = EE + j;
            xh[0][(s >> 5) * QSTR + (s & 31)] = h0[(size_t)b * HH + j];
        }
    } else if (tid < G4 + EE) {
        const int e = tid - G4;
        xh[0][e] = emb_lds[0][e];   // slot e < 20 -> quarter 0 offset e
    }
    __syncthreads();

#pragma unroll 1
    for (int t = 0; t < len; ++t) {
        const int cur = t & 1, nxt = cur ^ 1;
        if (tid < G4) {
            float acc[4][2];
#pragma unroll
            for (int g = 0; g < 4; ++g) { acc[g][0] = 0.f; acc[g][1] = 0.f; }
            const float* xc = &xh[cur][q * QSTR];
#pragma unroll
            for (int m = 0; m < 8; ++m) {
                float4 xv = *reinterpret_cast<const float4*>(xc + 4 * m);
#pragma unroll
                for (int g = 0; g < 4; ++g) {
                    fma_mix_lo(acc[g][0], w[g][2 * m],     xv.x);
                    fma_mix_hi(acc[g][1], w[g][2 * m],     xv.y);
                    fma_mix_lo(acc[g][0], w[g][2 * m + 1], xv.z);
                    fma_mix_hi(acc[g][1], w[g][2 * m + 1], xv.w);
                }
            }
            // quad allreduce: every lane gets all 4 gate totals
            float s_[4];
#pragma unroll
            for (int g = 0; g < 4; ++g) {
                float v = acc[g][0] + acc[g][1];
                v = dpp_xor1_add(v);
                v = dpp_xor2_add(v);
                s_[g] = v + biasv[g];
            }
            // lane q computes gate q's nonlinearity (one exp each, branchless)
            float sq = (q == 0) ? s_[0] : (q == 1) ? s_[1] : (q == 2) ? s_[2] : s_[3];
            float aa = (q == 2) ? 2.f : 1.f;
            float u  = fast_sig(aa * sq);
            float nq = u * aa - (aa - 1.f);       // q==2: tanh = 2*sig(2x)-1
            // gather to lane q=0: xor1 -> f, xor2 -> g, xor3 -> o
            float nf = dpp_mov<0xB1>(nq);
            float ng = dpp_mov<0x4E>(nq);
            float no = dpp_mov<0x1B>(nq);
            if (q == 0) {
                c_reg = nf * c_reg + nq * ng;
                float tc = 2.f * fast_sig(2.f * c_reg) - 1.f;
                float hv = no * tc;
                const int s = EE + j;
                xh[nxt][(s >> 5) * QSTR + (s & 31)] = hv;
                if (t == len - 1) hfin[j] = hv;
            }
        } else if (tid < G4 + EE) {
            const int e = tid - G4;
            if (t + 1 < TT) xh[nxt][e] = emb_lds[t + 1][e];
        }
        __syncthreads();
    }

    // fused MLP (single batch)
    if (tid < II) {
        float a = b1[tid];
        const float* w1r = W1 + tid * HH;
#pragma unroll
        for (int k = 0; k < HH; k += 4) {
            a += w1r[k] * hfin[k] + w1r[k + 1] * hfin[k + 1]
               + w1r[k + 2] * hfin[k + 2] + w1r[k + 3] * hfin[k + 3];
        }
        inter[tid] = fmaxf(a, 0.f);
    }
    __syncthreads();
    if (tid < AA) {
        float a = b2[tid];
        const float* w2r = W2 + tid * II;
#pragma unroll
        for (int k = 0; k < II; ++k) a += w2r[k] * inter[k];
        out[(size_t)b * AA + tid] = a;
    }
}

extern "C" void kernel_launch(void* const* d_in, const int* in_sizes, int n_in,
                              void* d_out, int out_size, void* d_ws, size_t ws_size,
                              hipStream_t stream) {
    const float* batch  = (const float*)d_in[0];
    const int*   lengths= (const int*)  d_in[1];
    const float* W_emb  = (const float*)d_in[2];
    const float* b_emb  = (const float*)d_in[3];
    const float* W_ih   = (const float*)d_in[4];
    const float* W_hh   = (const float*)d_in[5];
    const float* b_ih   = (const float*)d_in[6];
    const float* b_hh   = (const float*)d_in[7];
    const float* W1     = (const float*)d_in[8];
    const float* b1     = (const float*)d_in[9];
    const float* W2     = (const float*)d_in[10];
    const float* b2     = (const float*)d_in[11];
    const float* h0     = (const float*)d_in[12];
    const float* c0     = (const float*)d_in[13];
    float* out = (float*)d_out;

    int*       off   = (int*)d_ws;
    _Float16*  Bfrag = (_Float16*)((float*)d_ws + WS_BF_OFF);
    float*     emb   = (float*)d_ws + WS_EMB_OFF;

    k0_prep<<<1 + (NCHUNK * 2 * 64 * 8 + 511) / 512, 512, 0, stream>>>(lengths, W_emb, off, Bfrag);
    k1_embed<<<(BB * TT + 63) / 64, 256, 0, stream>>>(batch, off, Bfrag, b_emb, emb);
    k2_lstm<<<BB, 448, 0, stream>>>(emb, lengths, W_ih, W_hh, b_ih, b_hh,
                                    W1, b1, W2, b2, h0, c0, out);
}

// Round 10
// 432.431 us; speedup vs baseline: 2.2444x; 1.0494x over previous
//
#include <hip/hip_runtime.h>

#define BB 512
#define TT 200
#define VV 2048
#define EE 20
#define HH 100
#define G4 400   // 4*H
#define II 64
#define AA 32
#define NT 25    // 16-wide tiles over gate dim 400 (rows reordered r' = 4j+g)
#define NCHUNK 64

typedef _Float16 half8 __attribute__((ext_vector_type(8)));
typedef float    f32x4 __attribute__((ext_vector_type(4)));

// ---------------- workspace layout (4-byte units) ----------------
#define WS_BF_OFF    1024                        // k1 W_emb B-frags: 65536 half
#define WS_WIHF_OFF  (WS_BF_OFF + 32768)         // W_ih' B-frags: 12800 half
#define WS_WHHF_OFF  (WS_WIHF_OFF + 6400)        // W_hh' A-frags: 51200 half
#define WS_BIASC_OFF (WS_WHHF_OFF + 25600)       // 400 f  (b_ih+b_hh, r' order)
#define WS_EMB_OFF   (WS_BIASC_OFF + 400)        // emb, COMPACTED rows: 102400x20 f
#define WS_XG_OFF    (WS_EMB_OFF + 2048000)      // xg: 102720x400 f (padded)

// ---------------- Kernel 0: prefix-sum + all weight fragment packs ----------------
__global__ __launch_bounds__(512) void k0_prep(
    const int* __restrict__ lengths, const float* __restrict__ W_emb,
    const float* __restrict__ W_ih, const float* __restrict__ W_hh,
    const float* __restrict__ b_ih, const float* __restrict__ b_hh,
    int* __restrict__ off, _Float16* __restrict__ Bfrag,
    _Float16* __restrict__ Wihf, _Float16* __restrict__ Whhf,
    float* __restrict__ biasc)
{
    if (blockIdx.x == 0) {
        __shared__ int s[BB];
        int tid = threadIdx.x;
        s[tid] = lengths[tid];
        __syncthreads();
        for (int d = 1; d < BB; d <<= 1) {
            int v = (tid >= d) ? s[tid - d] : 0;
            __syncthreads();
            if (tid >= d) s[tid] += v;
            __syncthreads();
        }
        off[tid + 1] = s[tid];
        if (tid == 0) off[0] = 0;
        return;
    }
    int F = (blockIdx.x - 1) * 512 + threadIdx.x;
    if (F < 65536) {                       // k1 W_emb B-frags (unchanged)
        int e = F & 7, l = (F >> 3) & 63, nn = (F >> 9) & 1, c = F >> 10;
        int k = c * 32 + (l >> 4) * 8 + e;
        int col = nn * 16 + (l & 15);
        float v = (col < EE) ? W_emb[(size_t)col * VV + k] : 0.f;
        Bfrag[F] = (_Float16)v;
        return;
    }
    F -= 65536;
    if (F < 12800) {                       // W_ih' B-frags: [nt][lane][8]
        int e = F & 7, l = (F >> 3) & 63, nt = F >> 9;
        int rp = nt * 16 + (l & 15);       // r' = 4j+g
        int j = rp >> 2, g = rp & 3;
        int k = 8 * (l >> 4) + e;          // 0..31
        float v = (k < EE) ? W_ih[(size_t)(g * HH + j) * EE + k] : 0.f;
        Wihf[F] = (_Float16)v;
        return;
    }
    F -= 12800;
    if (F < 51200) {                       // W_hh' A-frags: [m][c][lane][8]
        int e = F & 7, l = (F >> 3) & 63, c = (F >> 9) & 3, m = F >> 11;
        int rp = m * 16 + (l & 15);
        int j = rp >> 2, g = rp & 3;
        int k = 32 * c + 8 * (l >> 4) + e; // 0..127
        float v = (k < HH) ? W_hh[(size_t)(g * HH + j) * HH + k] : 0.f;
        Whhf[F] = (_Float16)v;
        return;
    }
    F -= 51200;
    if (F < 400) {                         // biasc in r' order
        int j = F >> 2, g = F & 3;
        biasc[F] = b_ih[g * HH + j] + b_hh[g * HH + j];
    }
}

// ---------------- Kernel 1: embedding GEMM via MFMA fp16 -> COMPACTED emb ----------------
__global__ __launch_bounds__(256) void k1_embed(
    const float* __restrict__ batch, const int* __restrict__ off,
    const _Float16* __restrict__ Bfrag, const float* __restrict__ b_emb,
    float* __restrict__ emb)
{
    const int Nv = off[BB];
    if (blockIdx.x * 64 >= Nv) return;

    const int lane  = threadIdx.x & 63;
    const int wid   = threadIdx.x >> 6;
    const int rbase = blockIdx.x * 64 + wid * 16;

    int lrow = rbase + (lane & 15);
    int lr = (lrow < Nv) ? lrow : (Nv - 1);
    int lo = 0, hi = BB;
    while (lo + 1 < hi) {
        int mid = (lo + hi) >> 1;
        if (off[mid] <= lr) lo = mid; else hi = mid;
    }
    const int lroff = lo * TT + (lr - off[lo]);   // (b*TT + t): batch-source row

    const float* __restrict__ aptr = batch + (size_t)lroff * VV + ((lane >> 4) * 8);
    const half8* __restrict__ bptr = reinterpret_cast<const half8*>(Bfrag) + lane;

    f32x4 acc0 = {0.f, 0.f, 0.f, 0.f};
    f32x4 acc1 = {0.f, 0.f, 0.f, 0.f};

#pragma unroll 4
    for (int c = 0; c < NCHUNK; ++c) {
        float4 a0 = *reinterpret_cast<const float4*>(aptr + c * 32);
        float4 a1 = *reinterpret_cast<const float4*>(aptr + c * 32 + 4);
        half8 b0 = bptr[(c * 2 + 0) * 64];
        half8 b1 = bptr[(c * 2 + 1) * 64];
        half8 av;
        av[0] = (_Float16)a0.x; av[1] = (_Float16)a0.y;
        av[2] = (_Float16)a0.z; av[3] = (_Float16)a0.w;
        av[4] = (_Float16)a1.x; av[5] = (_Float16)a1.y;
        av[6] = (_Float16)a1.z; av[7] = (_Float16)a1.w;
        acc0 = __builtin_amdgcn_mfma_f32_16x16x32_f16(av, b0, acc0, 0, 0, 0);
        acc1 = __builtin_amdgcn_mfma_f32_16x16x32_f16(av, b1, acc1, 0, 0, 0);
    }

    const int col0 = lane & 15;
    const float bias0 = b_emb[col0];
    const float bias1 = (col0 < 4) ? b_emb[16 + col0] : 0.f;
#pragma unroll
    for (int r = 0; r < 4; ++r) {
        int srow = rbase + (lane >> 4) * 4 + r;   // compacted destination row
        if (srow < Nv) {
            emb[(size_t)srow * EE + col0] = acc0[r] + bias0;
            if (col0 < 4)
                emb[(size_t)srow * EE + 16 + col0] = acc1[r] + bias1;
        }
    }
}

// ---------------- Kernel 1b: xg = emb @ W_ih'^T + biasc  (compacted rows) ----------------
__global__ __launch_bounds__(256, 2) void k1_xg(
    const float* __restrict__ emb, const int* __restrict__ off,
    const _Float16* __restrict__ Wihf, const float* __restrict__ biasc,
    float* __restrict__ xg)
{
    __shared__ __align__(16) uint4 wl[NT * 64];   // 25600 B
    __shared__ float bl[G4];

    const int tid = threadIdx.x;
    const int Nv = off[BB];
    for (int i = tid; i < NT * 64; i += 256) wl[i] = reinterpret_cast<const uint4*>(Wihf)[i];
    for (int i = tid; i < G4; i += 256) bl[i] = biasc[i];
    __syncthreads();

    const int lane = tid & 63, wid = tid >> 6;
    const int T = blockIdx.x * 4 + wid;
    if (T * 16 >= Nv) return;

    const int lr = min(T * 16 + (lane & 15), Nv - 1);
    const int kb = (lane >> 4) * 8;
    const float* ap = emb + (size_t)lr * EE;
    float4 p0 = make_float4(0.f, 0.f, 0.f, 0.f), p1 = p0;
    if (kb < EE)     p0 = *reinterpret_cast<const float4*>(ap + kb);
    if (kb + 4 < EE) p1 = *reinterpret_cast<const float4*>(ap + kb + 4);
    half8 av;
    av[0] = (_Float16)p0.x; av[1] = (_Float16)p0.y;
    av[2] = (_Float16)p0.z; av[3] = (_Float16)p0.w;
    av[4] = (_Float16)p1.x; av[5] = (_Float16)p1.y;
    av[6] = (_Float16)p1.z; av[7] = (_Float16)p1.w;

    const int rbase = T * 16 + 4 * (lane >> 4);
    const int cl = lane & 15;
#pragma unroll
    for (int nt = 0; nt < NT; ++nt) {
        half8 bf = *reinterpret_cast<const half8*>(&wl[nt * 64 + lane]);
        f32x4 a = {0.f, 0.f, 0.f, 0.f};
        a = __builtin_amdgcn_mfma_f32_16x16x32_f16(av, bf, a, 0, 0, 0);
        float bias = bl[nt * 16 + cl];
#pragma unroll
        for (int r = 0; r < 4; ++r) {
            if (rbase + r < Nv)
                xg[(size_t)(rbase + r) * G4 + nt * 16 + cl] = a[r] + bias;
        }
    }
}

// ---------------- Kernel 2: MFMA LSTM scan, gates-in-lane, 1 barrier/step ----------------
__device__ __forceinline__ float fast_sig(float x) { return 1.f / (1.f + __expf(-x)); }
__device__ __forceinline__ float fast_tanh(float x) { return 2.f * fast_sig(2.f * x) - 1.f; }

#define STEP(T_, CUR_, XC_, XN_)  do {                                                        \
    uint4 rb0_ = *reinterpret_cast<const uint4*>(&bfrag[CUR_][0][lane][0]);                   \
    uint4 rb1_ = *reinterpret_cast<const uint4*>(&bfrag[CUR_][1][lane][0]);                   \
    uint4 rb2_ = *reinterpret_cast<const uint4*>(&bfrag[CUR_][2][lane][0]);                   \
    uint4 rb3_ = *reinterpret_cast<const uint4*>(&bfrag[CUR_][3][lane][0]);                   \
    _Pragma("unroll")                                                                         \
    for (int it = 0; it < 4; ++it) if (it < ntile)                                            \
        XN_[it] = *reinterpret_cast<const float4*>(xg + rowbase + (size_t)((T_) + 1) * G4 + xgoff[it]); \
    _Pragma("unroll")                                                                         \
    for (int it = 0; it < 4; ++it) if (it < ntile) {                                          \
        f32x4 acc = __builtin_bit_cast(f32x4, XC_[it]);                                       \
        acc = __builtin_amdgcn_mfma_f32_16x16x32_f16(af[it][0], __builtin_bit_cast(half8, rb0_), acc, 0, 0, 0); \
        acc = __builtin_amdgcn_mfma_f32_16x16x32_f16(af[it][1], __builtin_bit_cast(half8, rb1_), acc, 0, 0, 0); \
        acc = __builtin_amdgcn_mfma_f32_16x16x32_f16(af[it][2], __builtin_bit_cast(half8, rb2_), acc, 0, 0, 0); \
        acc = __builtin_amdgcn_mfma_f32_16x16x32_f16(af[it][3], __builtin_bit_cast(half8, rb3_), acc, 0, 0, 0); \
        float gi = fast_sig(acc[0]);                                                          \
        float gf = fast_sig(acc[1]);                                                          \
        float gg = fast_tanh(acc[2]);                                                         \
        float go = fast_sig(acc[3]);                                                          \
        cst[it] = gf * cst[it] + gi * gg;                                                     \
        float hv = go * fast_tanh(cst[it]);                                                   \
        int j_ = jidx[it];                                                                    \
        if ((T_) == len_n - 1) hfin[n][j_] = hv;                                              \
        int kk_ = j_ & 31;                                                                    \
        _Float16* hp_ = (_Float16*)&bfrag[(CUR_) ^ 1][j_ >> 5][((kk_ >> 3) << 4) | n][(kk_ & 7) >> 1]; \
        hp_[kk_ & 1] = (_Float16)hv;                                                          \
    }                                                                                         \
    __syncthreads();                                                                          \
} while (0)

__global__ __launch_bounds__(512, 2) void k2_lstm(
    const float* __restrict__ xg, const int* __restrict__ lengths,
    const int* __restrict__ off, const _Float16* __restrict__ Whhf,
    const float* __restrict__ W1, const float* __restrict__ b1,
    const float* __restrict__ W2, const float* __restrict__ b2,
    const float* __restrict__ h0, const float* __restrict__ c0,
    float* __restrict__ out)
{
    __shared__ __align__(16) unsigned int bfrag[2][4][64][4];  // 8 KB fp16 B-frags
    __shared__ float hfin[16][HH];
    __shared__ float inter[16][II];
    __shared__ int len_s[16], off_s[16];

    const int tid  = threadIdx.x;
    const int lane = tid & 63;
    const int w    = tid >> 6;
    const int b0   = blockIdx.x * 16;
    const int n    = lane & 15, rg = lane >> 4;

    if (tid < 16) {
        len_s[tid] = lengths[b0 + tid];
        off_s[tid] = off[b0 + tid];
    }
    for (int i = tid; i < 2 * 4 * 64 * 4; i += 512) (&bfrag[0][0][0][0])[i] = 0u;
    __syncthreads();

    int tmax = 0;
#pragma unroll
    for (int k = 0; k < 16; ++k) tmax = max(tmax, len_s[k]);

    const int ntile = (w == 7) ? 4 : 3;
    const int m0    = (w < 7) ? 3 * w : 21;
    const int len_n = len_s[n];
    const size_t rowbase = (size_t)off_s[n] * G4;

    half8 af[4][4];
    float cst[4];
    int   jidx[4], xgoff[4];
    float4 xgA[4], xgB[4];
#pragma unroll
    for (int it = 0; it < 4; ++it) if (it < ntile) {
        const int m = m0 + it;
#pragma unroll
        for (int c = 0; c < 4; ++c)
            af[it][c] = reinterpret_cast<const half8*>(Whhf)[((m * 4 + c) * 64) + lane];
        const int j = 4 * m + rg;
        jidx[it]  = j;
        xgoff[it] = 16 * m + 4 * rg;
        cst[it] = c0[(size_t)(b0 + n) * HH + j];
        float hv = h0[(size_t)(b0 + n) * HH + j];
        int kk = j & 31;
        _Float16* hp = (_Float16*)&bfrag[0][j >> 5][((kk >> 3) << 4) | n][(kk & 7) >> 1];
        hp[kk & 1] = (_Float16)hv;
        xgA[it] = *reinterpret_cast<const float4*>(xg + rowbase + xgoff[it]);
    }
    __syncthreads();

    for (int t = 0; t < tmax; t += 2) {
        STEP(t, 0, xgA, xgB);
        if (t + 1 < tmax) STEP(t + 1, 1, xgB, xgA);
    }

    // fused MLP over the 16 batches
    for (int o = tid; o < 16 * II; o += 512) {
        int nn = o >> 6, i = o & 63;
        float a = b1[i];
        const float* w1r = W1 + i * HH;
        const float* hr  = &hfin[nn][0];
#pragma unroll
        for (int k = 0; k < HH; k += 4) {
            a += w1r[k] * hr[k] + w1r[k + 1] * hr[k + 1]
               + w1r[k + 2] * hr[k + 2] + w1r[k + 3] * hr[k + 3];
        }
        inter[nn][i] = fmaxf(a, 0.f);
    }
    __syncthreads();
    for (int o = tid; o < 16 * AA; o += 512) {
        int nn = o >> 5, ai = o & 31;
        float a = b2[ai];
        const float* w2r = W2 + ai * II;
#pragma unroll
        for (int k = 0; k < II; ++k) a += w2r[k] * inter[nn][k];
        out[(size_t)(b0 + nn) * AA + ai] = a;
    }
}

extern "C" void kernel_launch(void* const* d_in, const int* in_sizes, int n_in,
                              void* d_out, int out_size, void* d_ws, size_t ws_size,
                              hipStream_t stream) {
    const float* batch  = (const float*)d_in[0];
    const int*   lengths= (const int*)  d_in[1];
    const float* W_emb  = (const float*)d_in[2];
    const float* b_emb  = (const float*)d_in[3];
    const float* W_ih   = (const float*)d_in[4];
    const float* W_hh   = (const float*)d_in[5];
    const float* b_ih   = (const float*)d_in[6];
    const float* b_hh   = (const float*)d_in[7];
    const float* W1     = (const float*)d_in[8];
    const float* b1     = (const float*)d_in[9];
    const float* W2     = (const float*)d_in[10];
    const float* b2     = (const float*)d_in[11];
    const float* h0     = (const float*)d_in[12];
    const float* c0     = (const float*)d_in[13];
    float* out = (float*)d_out;

    int*       off   = (int*)d_ws;
    float*     wsf   = (float*)d_ws;
    _Float16*  Bfrag = (_Float16*)(wsf + WS_BF_OFF);
    _Float16*  Wihf  = (_Float16*)(wsf + WS_WIHF_OFF);
    _Float16*  Whhf  = (_Float16*)(wsf + WS_WHHF_OFF);
    float*     biasc = wsf + WS_BIASC_OFF;
    float*     emb   = wsf + WS_EMB_OFF;
    float*     xg    = wsf + WS_XG_OFF;

    k0_prep<<<255, 512, 0, stream>>>(lengths, W_emb, W_ih, W_hh, b_ih, b_hh,
                                     off, Bfrag, Wihf, Whhf, biasc);
    k1_embed<<<(BB * TT + 63) / 64, 256, 0, stream>>>(batch, off, Bfrag, b_emb, emb);
    k1_xg<<<(BB * TT / 16 + 3) / 4, 256, 0, stream>>>(emb, off, Wihf, biasc, xg);
    k2_lstm<<<BB / 16, 512, 0, stream>>>(xg, lengths, off, Whhf,
                                         W1, b1, W2, b2, h0, c0, out);
}